// Round 8
// baseline (1318.191 us; speedup 1.0000x reference)
//
#include <hip/hip_runtime.h>
#include <hip/hip_fp16.h>

// Problem constants: B=16, G=8192, C=16, S=8, L=3, m=1, infer_step=4
constexpr int B = 16;
constexpr int G = 8192;
constexpr int C = 16;
constexpr int S = 8;
constexpr int L = 3;
constexpr int STEPS = 4;
constexpr int NSLOT = 64;                 // atomic-max slots, one per 64B line
constexpr int ARR = NSLOT * 16;           // 1024 floats per slot-array
constexpr int NBLK = 1024;                // 4 blocks per CU (resource-guaranteed)
constexpr int TPB  = 512;                 // 8 waves/block -> 32 waves/CU
constexpr int WPB  = TPB / 64;            // 8 waves
constexpr int IDXG = C * S * L;           // 384 u16 per g

#define K_E   144.269504088896f   // 1/(gamma*ln2), gamma=0.01
#define GLN2  0.00693147180560f   // gamma*ln2

typedef float f4 __attribute__((ext_vector_type(4)));

__device__ __forceinline__ float fexp2(float x){ return __builtin_amdgcn_exp2f(x); }
__device__ __forceinline__ float flog2(float x){ return __builtin_amdgcn_logf(x); }

__device__ __forceinline__ void atomicMaxF(float* p, float v){
    atomicMax(reinterpret_cast<unsigned int*>(p), __float_as_uint(v));
}

__device__ __forceinline__ float waveMax(float v){
    #pragma unroll
    for (int off = 32; off > 0; off >>= 1)
        v = fmaxf(v, __shfl_down(v, off));
    return v;
}

// Wave-cooperative reduce of 64 spread slots: one gather, shfl_xor tree, broadcast.
__device__ __forceinline__ float waveSlotMax(const float* __restrict__ slots){
    float v = slots[(threadIdx.x & 63) << 4];
    v = fmaxf(v, __shfl_xor(v, 32));
    v = fmaxf(v, __shfl_xor(v, 16));
    v = fmaxf(v, __shfl_xor(v, 8));
    v = fmaxf(v, __shfl_xor(v, 4));
    v = fmaxf(v, __shfl_xor(v, 2));
    v = fmaxf(v, __shfl_xor(v, 1));
    return __builtin_amdgcn_readfirstlane(v);
}

// Grid barrier, monotonic epochs (bar memset to 0 each launch). Proven R6/R7.
__device__ __forceinline__ void gridBar(unsigned* bar, unsigned target){
    __syncthreads();
    if (threadIdx.x == 0){
        __hip_atomic_fetch_add(bar, 1u, __ATOMIC_RELEASE, __HIP_MEMORY_SCOPE_AGENT);
        while (__hip_atomic_load(bar, __ATOMIC_ACQUIRE, __HIP_MEMORY_SCOPE_AGENT) < target)
            __builtin_amdgcn_s_sleep(2);
    }
    __syncthreads();
}

// ws float layout:
//   [0..15]          wstar
//   [16..12304)      slots: step s -> {Ls, Hu, T} arrays of 1024 floats
//   [12304..12320)   barrier counter line
//   [12320..)        TA, TB (fp32 state), TAh, TBh (fp16 shadows)

__global__ void __launch_bounds__(TPB, 8) fused_kernel(
        const float* __restrict__ x, const int* __restrict__ I,
        const float* __restrict__ W,
        float* __restrict__ wstar, float* __restrict__ slots,
        unsigned* __restrict__ bar,
        float* __restrict__ TA, float* __restrict__ TB,
        __half* __restrict__ TAh, __half* __restrict__ TBh,
        float* __restrict__ out)
{
    const int tix  = threadIdx.x;
    const int gt   = blockIdx.x * TPB + tix;
    const int lane = tix & 63;
    const int wib  = tix >> 6;                    // wave in block, 0..7
    const int g    = blockIdx.x * WPB + wib;      // one g per wave, 0..8191
    const int j    = lane >> 4;
    const int b    = lane & 15;

    // Per-wave index slab (768 B), staged once, reused all 4 steps.
    __shared__ __align__(16) ushort sIdx[WPB * IDXG];   // 6 KB/block
    ushort* myIdx = sIdx + wib * IDXG;

    // ---- prep: stage indices to LDS (u16), transpose x, init slots/wstar
    #pragma unroll
    for (int i = lane; i < IDXG; i += 64){        // 6 iterations
        int c = i / 24;
        int t = i - c*24;
        myIdx[i] = (ushort)I[((size_t)(c*G + g))*24 + t];
    }
    if (gt < B*G){
        int bb = gt >> 13;
        int gg = gt & (G-1);
        float v = x[gt];
        TA[gg*B + bb]  = v;
        TAh[gg*B + bb] = __float2half(v);
    }
    if (gt < 12*ARR) slots[gt] = 0.f;
    if (gt == 0){
        float mx = -1e30f;
        for (int c = 0; c < C; c++) mx = fmaxf(mx, W[c]);
        float e[C]; float s = 0.f;
        for (int c = 0; c < C; c++){ e[c] = fexp2((W[c]-mx)*1.44269504089f); s += e[c]; }
        for (int c = 0; c < C; c++) wstar[c] = e[c] / s;
    }

    unsigned tgt = NBLK;
    gridBar(bar, tgt);

    const f4 wst4 = *(const f4*)(wstar + j*4);    // valid after barrier

    float*  Tc  = TA;  float*  Tn  = TB;
    __half* Tch = TAh; __half* Tnh = TBh;
    float scPrev = 1.0f;

    for (int s = 0; s < STEPS; s++){
        float* slotLs = slots + (s*3 + 0)*ARR;
        float* slotHu = slots + (s*3 + 1)*ARR;
        float* slotT  = slots + (s*3 + 2)*ARR;

        // ---- clause phase: idx from LDS, fp16 state gathers
        const float sc3 = scPrev * scPrev * scPrev;
        float humix = 0.f, lsm = 0.f;
        #pragma unroll 2
        for (int k = 0; k < 4; k++){
            const int c = j*4 + k;
            const uint4* p = (const uint4*)(myIdx + c*24);
            uint4 d0 = p[0], d1 = p[1], d2 = p[2];
            unsigned dw[12] = {d0.x,d0.y,d0.z,d0.w, d1.x,d1.y,d1.z,d1.w,
                               d2.x,d2.y,d2.z,d2.w};
            float gv[S*L];
            #pragma unroll
            for (int i = 0; i < 12; i++){
                gv[2*i]   = __half2float(Tch[(int)(dw[i] & 0xFFFFu)*B + b]);
                gv[2*i+1] = __half2float(Tch[(int)(dw[i] >> 16)*B + b]);
            }
            float body[S];
            #pragma unroll
            for (int q = 0; q < S; q++) body[q] = gv[3*q] * gv[3*q+1] * gv[3*q+2] * sc3;

            float m = body[0];
            #pragma unroll
            for (int q = 1; q < S; q++) m = fmaxf(m, body[q]);
            float sum = 0.f;
            #pragma unroll
            for (int q = 0; q < S; q++) sum += fexp2((body[q] - m) * K_E);
            float ls = m + GLN2 * flog2(sum);

            lsm = fmaxf(lsm, ls);
            humix = __builtin_fmaf(wst4[k], ls, humix);
        }
        humix += __shfl_xor(humix, 16);   // reduce over j-subgroups
        humix += __shfl_xor(humix, 32);

        float wl = waveMax(lsm);
        float wh = waveMax(humix);        // humix replicated; max = value
        if (lane == 0){
            atomicMaxF(&slotLs[(g & (NSLOT-1)) << 4], wl);
            atomicMaxF(&slotHu[(g & (NSLOT-1)) << 4], wh);
        }
        tgt += NBLK; gridBar(bar, tgt);

        // ---- combine phase (Hu stays in registers; lanes 0-15 active)
        const float scA = 1.0f / fmaxf(waveSlotMax(slotLs), 1.0f);
        const float scB = 1.0f / fmaxf(scA * waveSlotMax(slotHu), 1.0f);
        float v = 0.f;
        if (lane < 16){
            float r  = humix * (scA * scB);
            float Rn = Tc[g*B + b] * scPrev;
            float M  = fmaxf(Rn, r);
            v = M + GLN2 * flog2(fexp2((Rn-M)*K_E) + fexp2((r-M)*K_E));
            if (s < STEPS-1){
                Tn[g*B + b]  = v;
                Tnh[g*B + b] = __float2half(v);
            }
        }
        float wm = waveMax(v);
        if (lane == 0) atomicMaxF(&slotT[(g & (NSLOT-1)) << 4], wm);
        tgt += NBLK; gridBar(bar, tgt);

        scPrev = 1.0f / fmaxf(waveSlotMax(slotT), 1.0f);

        if (s == STEPS-1){
            if (lane < 16) out[b*G + g] = v * scPrev;   // out[b*G+g]
        } else {
            float*  tf = Tc;  Tc  = Tn;  Tn  = tf;
            __half* th = Tch; Tch = Tnh; Tnh = th;
        }
    }
}

extern "C" void kernel_launch(void* const* d_in, const int* in_sizes, int n_in,
                              void* d_out, int out_size, void* d_ws, size_t ws_size,
                              hipStream_t stream) {
    const float* x = (const float*)d_in[0];
    const float* W = (const float*)d_in[1];
    const int*   I = (const int*)d_in[2];
    // d_in[3] = infer_step (device scalar); fixed at 4 by setup_inputs.

    float* ws     = (float*)d_ws;
    float* wstar  = ws;                          // 16
    float* slots  = ws + 16;                     // 12*1024
    unsigned* bar = (unsigned*)(ws + 12304);     // one 64B line
    float* TA     = ws + 12320;
    float* TB     = TA + (size_t)G*B;
    __half* TAh   = (__half*)(TB + (size_t)G*B);
    __half* TBh   = TAh + (size_t)G*B;

    float* out = (float*)d_out;

    hipMemsetAsync(bar, 0, 64, stream);   // reset barrier epochs (graph-capturable)
    fused_kernel<<<NBLK, TPB, 0, stream>>>(x, I, W, wstar, slots, bar,
                                           TA, TB, TAh, TBh, out);
}

// Round 9
// 149.287 us; speedup vs baseline: 8.8299x; 8.8299x over previous
//
#include <hip/hip_runtime.h>
#include <hip/hip_fp16.h>

// Problem constants: B=16, G=8192, C=16, S=8, L=3, m=1, infer_step=4
constexpr int B = 16;
constexpr int G = 8192;
constexpr int C = 16;
constexpr int S = 8;
constexpr int L = 3;
constexpr int STEPS = 4;
constexpr int NSLOT = 64;        // max-slots, one per 64B line
constexpr int ARR = NSLOT * 16;  // 1024 floats per slot-array

#define K_E   144.269504088896f   // 1/(gamma*ln2), gamma=0.01
#define GLN2  0.00693147180560f   // gamma*ln2

typedef float f4 __attribute__((ext_vector_type(4)));

__device__ __forceinline__ float fexp2(float x){ return __builtin_amdgcn_exp2f(x); }
__device__ __forceinline__ float flog2(float x){ return __builtin_amdgcn_logf(x); }

__device__ __forceinline__ void atomicMaxF(float* p, float v){
    atomicMax(reinterpret_cast<unsigned int*>(p), __float_as_uint(v));
}

__device__ __forceinline__ float waveMax(float v){
    #pragma unroll
    for (int off = 32; off > 0; off >>= 1)
        v = fmaxf(v, __shfl_down(v, off));
    return v;
}

// Wave-cooperative reduce of 64 spread slots: one gather, shfl_xor tree, broadcast.
__device__ __forceinline__ float waveSlotMax(const float* __restrict__ slots){
    float v = slots[(threadIdx.x & 63) << 4];
    v = fmaxf(v, __shfl_xor(v, 32));
    v = fmaxf(v, __shfl_xor(v, 16));
    v = fmaxf(v, __shfl_xor(v, 8));
    v = fmaxf(v, __shfl_xor(v, 4));
    v = fmaxf(v, __shfl_xor(v, 2));
    v = fmaxf(v, __shfl_xor(v, 1));
    return __builtin_amdgcn_readfirstlane(v);
}

// ---------------------------------------------------------------------------
// prep: fused pack (I -> u16), transpose (x -> T0 fp32 + fp16 shadow), init.
template<bool PK>
__global__ __launch_bounds__(256) void prep_kernel(
        const float* __restrict__ x, const int* __restrict__ I,
        const float* __restrict__ W,
        float* __restrict__ wstar, float* __restrict__ slots,
        ushort* __restrict__ Ipk,
        float* __restrict__ T0, __half* __restrict__ T0h)
{
    constexpr int NPACK = PK ? (C*G*S*L/4)/256 : 0;   // 3072 or 0
    const int bid = blockIdx.x;
    if (PK && bid < NPACK){
        int t = bid*256 + threadIdx.x;
        int4 v = ((const int4*)I)[t];
        ushort4 o;
        o.x = (ushort)v.x; o.y = (ushort)v.y; o.z = (ushort)v.z; o.w = (ushort)v.w;
        ((ushort4*)Ipk)[t] = o;
    } else if (bid < NPACK + (B*G)/256){
        int t = (bid - NPACK)*256 + threadIdx.x;  // t = b*G + g
        int b = t >> 13;
        int g = t & (G-1);
        float v = x[t];
        T0[g*B + b] = v;
        if (PK) T0h[g*B + b] = __float2half(v);
    } else {
        int t = threadIdx.x;
        for (int i = t; i < 13*ARR; i += 256) slots[i] = 0.f;
        if (t == 0){
            slots[12*ARR] = 1.0f;   // identity prev-max array
            float mx = -1e30f;
            for (int c = 0; c < C; c++) mx = fmaxf(mx, W[c]);
            float e[C]; float s = 0.f;
            for (int c = 0; c < C; c++){ e[c] = fexp2((W[c]-mx)*1.44269504089f); s += e[c]; }
            for (int c = 0; c < C; c++) wstar[c] = e[c] / s;
        }
    }
}

// ---------------------------------------------------------------------------
// b-pair clause helpers: 24 half2 gathers for one clause, then LSE for both b's.
__device__ __forceinline__ void loadPair(const __half* __restrict__ Th,
                                         const unsigned* dw, int bp, __half2* h){
    #pragma unroll
    for (int i = 0; i < 12; i++){
        h[2*i]   = *(const __half2*)(Th + (dw[i] & 0xFFFFu)*B + 2*bp);
        h[2*i+1] = *(const __half2*)(Th + (dw[i] >> 16)*B + 2*bp);
    }
}

__device__ __forceinline__ void procPair(const __half2* h, float sc3, float wc,
                                         float& hux, float& huy, float& lsm){
    float bx[S], by[S];
    #pragma unroll
    for (int s = 0; s < S; s++){
        float2 u = __half22float2(h[3*s+0]);
        float2 v = __half22float2(h[3*s+1]);
        float2 w = __half22float2(h[3*s+2]);
        bx[s] = u.x*v.x*w.x*sc3;
        by[s] = u.y*v.y*w.y*sc3;
    }
    float mx = bx[0], my = by[0];
    #pragma unroll
    for (int s = 1; s < S; s++){ mx = fmaxf(mx, bx[s]); my = fmaxf(my, by[s]); }
    float sx = 0.f, sy = 0.f;
    #pragma unroll
    for (int s = 0; s < S; s++){
        sx += fexp2((bx[s]-mx)*K_E);
        sy += fexp2((by[s]-my)*K_E);
    }
    float lx = mx + GLN2*flog2(sx);
    float ly = my + GLN2*flog2(sy);
    lsm = fmaxf(lsm, fmaxf(lx, ly));
    hux = __builtin_fmaf(wc, lx, hux);
    huy = __builtin_fmaf(wc, ly, huy);
}

// Clause: one wave per g, lane = j*8+bp. Lane gathers half2 (2 b's) for clauses
// c=j and c=j+8: 48 half2 loads staged in registers -> deep MLP (R5 had ~8).
__global__ __launch_bounds__(256) void clause_h2(
        const __half*  __restrict__ Th,     // (G,B) fp16 shadow of state
        const ushort*  __restrict__ I16,    // packed indices
        const float*   __restrict__ wstar,
        const float*   __restrict__ slotPrev,
        float* __restrict__ slotLs,
        float* __restrict__ slotHu,
        float* __restrict__ Hu)             // (G,B) fp32 out
{
    const int lane = threadIdx.x & 63;
    const int g    = blockIdx.x*4 + (threadIdx.x >> 6);
    const int j    = lane >> 3;          // 0..7 -> clauses j and j+8
    const int bp   = lane & 7;           // b-pair: b = 2bp, 2bp+1

    const float scPrev = 1.0f / fmaxf(waveSlotMax(slotPrev), 1.0f);
    const float sc3 = scPrev * scPrev * scPrev;
    const float w0 = wstar[j], w1 = wstar[j+8];

    const uint4* p0 = (const uint4*)(I16 + (size_t)(j*G + g)*(S*L));
    const uint4* p1 = (const uint4*)(I16 + (size_t)((j+8)*G + g)*(S*L));
    uint4 q0 = p0[0], q1 = p0[1], q2 = p0[2];
    uint4 r0 = p1[0], r1 = p1[1], r2 = p1[2];
    unsigned dA[12] = {q0.x,q0.y,q0.z,q0.w, q1.x,q1.y,q1.z,q1.w, q2.x,q2.y,q2.z,q2.w};
    unsigned dB[12] = {r0.x,r0.y,r0.z,r0.w, r1.x,r1.y,r1.z,r1.w, r2.x,r2.y,r2.z,r2.w};

    __half2 h0[24], h1[24];
    loadPair(Th, dA, bp, h0);
    loadPair(Th, dB, bp, h1);

    float hux = 0.f, huy = 0.f, lsm = 0.f;
    procPair(h0, sc3, w0, hux, huy, lsm);
    procPair(h1, sc3, w1, hux, huy, lsm);

    // reduce over j (lane bits 3..5)
    hux += __shfl_xor(hux, 8); hux += __shfl_xor(hux, 16); hux += __shfl_xor(hux, 32);
    huy += __shfl_xor(huy, 8); huy += __shfl_xor(huy, 16); huy += __shfl_xor(huy, 32);

    if (lane < 8)   // j==0 lanes: 8 x float2 = one 64B line
        ((float2*)(Hu + (size_t)g*B))[bp] = make_float2(hux, huy);

    float wl = waveMax(lsm);
    float wh = waveMax(fmaxf(hux, huy));
    if (lane == 0){
        atomicMaxF(&slotLs[(g & (NSLOT-1)) << 4], wl);
        atomicMaxF(&slotHu[(g & (NSLOT-1)) << 4], wh);
    }
}

// Fallback clause (fp32 state, unpacked int32 I) — R4-proven path.
__global__ __launch_bounds__(256) void clause_f(
        const float* __restrict__ Tin,
        const int*   __restrict__ I32,
        const float* __restrict__ wstar,
        const float* __restrict__ slotPrev,
        float* __restrict__ slotLs,
        float* __restrict__ slotHu,
        float* __restrict__ Hu)
{
    const int lane = threadIdx.x & 63;
    const int g    = blockIdx.x*4 + (threadIdx.x >> 6);
    const int j    = lane >> 4;
    const int b    = lane & 15;

    const float scPrev = 1.0f / fmaxf(waveSlotMax(slotPrev), 1.0f);
    const float sc3 = scPrev * scPrev * scPrev;
    const f4 wst4 = *(const f4*)(wstar + j*4);

    float humix = 0.f, lsmax = 0.f;
    #pragma unroll 2
    for (int k = 0; k < 4; k++){
        const int c = j*4 + k;
        const int4* p = (const int4*)(I32 + (size_t)(c*G + g)*(S*L));
        int idx[S*L];
        #pragma unroll
        for (int i = 0; i < 6; i++){
            int4 v = p[i];
            idx[4*i] = v.x; idx[4*i+1] = v.y; idx[4*i+2] = v.z; idx[4*i+3] = v.w;
        }
        float gv[S*L];
        #pragma unroll
        for (int t = 0; t < S*L; t++) gv[t] = Tin[idx[t]*B + b];

        float body[S];
        #pragma unroll
        for (int s = 0; s < S; s++) body[s] = gv[3*s] * gv[3*s+1] * gv[3*s+2] * sc3;

        float m = body[0];
        #pragma unroll
        for (int s = 1; s < S; s++) m = fmaxf(m, body[s]);
        float sum = 0.f;
        #pragma unroll
        for (int s = 0; s < S; s++) sum += fexp2((body[s] - m) * K_E);
        float ls = m + GLN2 * flog2(sum);

        lsmax = fmaxf(lsmax, ls);
        humix = __builtin_fmaf(wst4[k], ls, humix);
    }

    humix += __shfl_xor(humix, 16);
    humix += __shfl_xor(humix, 32);
    if (lane < 16) Hu[(size_t)g*B + lane] = humix;

    float wl = waveMax(lsmax);
    float wh = waveMax(humix);
    if (lane == 0){
        atomicMaxF(&slotLs[(g & (NSLOT-1)) << 4], wl);
        atomicMaxF(&slotHu[(g & (NSLOT-1)) << 4], wh);
    }
}

// ---------------------------------------------------------------------------
// Combine: r = (scA*Hu)/max(scA*gmaxHu,1); T = gamma*LSE2(Rn, r); track gmax(T).
template<bool PK>
__global__ __launch_bounds__(256) void combine_kernel(
        const float* __restrict__ Hu,
        const float* __restrict__ Tin,
        const float* __restrict__ slotLs,
        const float* __restrict__ slotHu,
        const float* __restrict__ slotPrev,
        float* __restrict__ Tout,
        __half* __restrict__ Tout16,
        float* __restrict__ slotT)
{
    const float scA = 1.0f / fmaxf(waveSlotMax(slotLs), 1.0f);
    const float scB = 1.0f / fmaxf(scA * waveSlotMax(slotHu), 1.0f);
    const float scP = 1.0f / fmaxf(waveSlotMax(slotPrev), 1.0f);

    const int t = blockIdx.x*256 + threadIdx.x;   // over G*B
    float r  = Hu[t] * (scA * scB);
    float Rn = Tin[t] * scP;
    float M  = fmaxf(Rn, r);
    float v  = M + GLN2 * flog2(fexp2((Rn-M)*K_E) + fexp2((r-M)*K_E));
    Tout[t] = v;
    if (PK) Tout16[t] = __float2half(v);
    float wm = waveMax(v);
    if ((threadIdx.x & 63) == 0)
        atomicMaxF(&slotT[(blockIdx.x & (NSLOT-1)) << 4], wm);
}

// final: out[b*G+g] = T[g*B+b] / max(gmaxT,1)
__global__ void output_kernel(const float* __restrict__ T, const float* __restrict__ slotT,
                              float* __restrict__ out){
    float sc = 1.0f / fmaxf(waveSlotMax(slotT), 1.0f);
    int tid = blockIdx.x*256 + threadIdx.x;   // b*G+g
    int b = tid >> 13;
    int g = tid & (G-1);
    out[tid] = T[g*B + b] * sc;
}

extern "C" void kernel_launch(void* const* d_in, const int* in_sizes, int n_in,
                              void* d_out, int out_size, void* d_ws, size_t ws_size,
                              hipStream_t stream) {
    const float* x = (const float*)d_in[0];
    const float* W = (const float*)d_in[1];
    const int*   I = (const int*)d_in[2];
    // d_in[3] = infer_step (device scalar); fixed at 4 by setup_inputs.

    const size_t baseF  = 16 + 13*ARR;           // wstar + slots
    const size_t packF  = (size_t)C*G*S*L / 2;   // packed I, in float units
    const size_t stateF = (size_t)G*B;
    const size_t halfF  = (size_t)G*B / 2;       // fp16 shadow, in float units
    const bool packed = ws_size >= (baseF + packF + 3*stateF + 2*halfF) * sizeof(float);

    float* ws    = (float*)d_ws;
    float* wstar = ws;
    float* slots = ws + 16;
    ushort* Ipk  = (ushort*)(ws + baseF);
    float* T0    = ws + baseF + (packed ? packF : 0);
    float* T1    = T0 + stateF;
    float* Hu    = T1 + stateF;
    __half* T0h  = (__half*)(Hu + stateF);
    __half* T1h  = T0h + G*B;

    float* out = (float*)d_out;

    if (packed){
        prep_kernel<true><<<(C*G*S*L/4)/256 + (B*G)/256 + 1, 256, 0, stream>>>(
            x, I, W, wstar, slots, Ipk, T0, T0h);
    } else {
        prep_kernel<false><<<(B*G)/256 + 1, 256, 0, stream>>>(
            x, I, W, wstar, slots, Ipk, T0, T0h);
    }

    float* bufs[2]   = {T0, T1};
    __half* bufsh[2] = {T0h, T1h};
    for (int s = 0; s < STEPS; s++){
        float*  Tin   = bufs[s & 1];
        float*  Tout  = bufs[(s+1) & 1];
        __half* Tinh  = bufsh[s & 1];
        __half* Touth = bufsh[(s+1) & 1];
        float* slotLs = slots + (s*3 + 0)*ARR;
        float* slotHu = slots + (s*3 + 1)*ARR;
        float* slotT  = slots + (s*3 + 2)*ARR;
        const float* slotPrev = (s == 0) ? (slots + 12*ARR) : (slots + ((s-1)*3 + 2)*ARR);
        if (packed){
            clause_h2<<<G/4, 256, 0, stream>>>(Tinh, Ipk, wstar, slotPrev,
                                               slotLs, slotHu, Hu);
            combine_kernel<true><<<(G*B)/256, 256, 0, stream>>>(Hu, Tin, slotLs, slotHu,
                                                                slotPrev, Tout, Touth, slotT);
        } else {
            clause_f<<<G/4, 256, 0, stream>>>(Tin, I, wstar, slotPrev,
                                              slotLs, slotHu, Hu);
            combine_kernel<false><<<(G*B)/256, 256, 0, stream>>>(Hu, Tin, slotLs, slotHu,
                                                                 slotPrev, Tout, Touth, slotT);
        }
    }
    output_kernel<<<(B*G)/256, 256, 0, stream>>>(bufs[STEPS & 1],
                                                 slots + ((STEPS-1)*3 + 2)*ARR, out);
}

// Round 10
// 78.024 us; speedup vs baseline: 16.8947x; 1.9133x over previous
//
#include <hip/hip_runtime.h>
#include <hip/hip_fp16.h>

// Problem constants: B=16, G=8192, C=16, S=8, L=3, m=1, infer_step=4
constexpr int B = 16;
constexpr int G = 8192;
constexpr int C = 16;
constexpr int S = 8;
constexpr int L = 3;
constexpr int STEPS = 4;
constexpr int NSLOT = 64;        // max-slots, one per 64B line
constexpr int ARR = NSLOT * 16;  // 1024 floats per slot-array

#define K_E   144.269504088896f   // 1/(gamma*ln2), gamma=0.01
#define GLN2  0.00693147180560f   // gamma*ln2

typedef float f4 __attribute__((ext_vector_type(4)));

__device__ __forceinline__ float fexp2(float x){ return __builtin_amdgcn_exp2f(x); }
__device__ __forceinline__ float flog2(float x){ return __builtin_amdgcn_logf(x); }

__device__ __forceinline__ void atomicMaxF(float* p, float v){
    atomicMax(reinterpret_cast<unsigned int*>(p), __float_as_uint(v));
}

__device__ __forceinline__ float waveMax(float v){
    #pragma unroll
    for (int off = 32; off > 0; off >>= 1)
        v = fmaxf(v, __shfl_down(v, off));
    return v;
}

// Wave-cooperative reduce of 64 spread slots: one gather, shfl_xor tree, broadcast.
__device__ __forceinline__ float waveSlotMax(const float* __restrict__ slots){
    float v = slots[(threadIdx.x & 63) << 4];
    v = fmaxf(v, __shfl_xor(v, 32));
    v = fmaxf(v, __shfl_xor(v, 16));
    v = fmaxf(v, __shfl_xor(v, 8));
    v = fmaxf(v, __shfl_xor(v, 4));
    v = fmaxf(v, __shfl_xor(v, 2));
    v = fmaxf(v, __shfl_xor(v, 1));
    return __builtin_amdgcn_readfirstlane(v);
}

// ---------------------------------------------------------------------------
// prep: pack I -> u16, transpose x -> T0 fp32 + bh-major fp16 shadow, init.
// Shadow layout: Thh[bh][g][8] halves, bh = b>>3, bl = b&7.
template<bool PK>
__global__ __launch_bounds__(256) void prep_kernel(
        const float* __restrict__ x, const int* __restrict__ I,
        const float* __restrict__ W,
        float* __restrict__ wstar, float* __restrict__ slots,
        ushort* __restrict__ Ipk,
        float* __restrict__ T0, __half* __restrict__ Thh0)
{
    constexpr int NPACK = PK ? (C*G*S*L/4)/256 : 0;   // 3072 or 0
    const int bid = blockIdx.x;
    if (PK && bid < NPACK){
        int t = bid*256 + threadIdx.x;
        int4 v = ((const int4*)I)[t];
        ushort4 o;
        o.x = (ushort)v.x; o.y = (ushort)v.y; o.z = (ushort)v.z; o.w = (ushort)v.w;
        ((ushort4*)Ipk)[t] = o;
    } else if (bid < NPACK + (B*G)/256){
        int t = (bid - NPACK)*256 + threadIdx.x;  // t = b*G + g
        int b = t >> 13;
        int g = t & (G-1);
        float v = x[t];
        T0[g*B + b] = v;
        if (PK) Thh0[((size_t)(b>>3)*G + g)*8 + (b&7)] = __float2half(v);
    } else {
        int t = threadIdx.x;
        for (int i = t; i < 13*ARR; i += 256) slots[i] = 0.f;
        if (t == 0){
            slots[12*ARR] = 1.0f;   // identity prev-max array
            float mx = -1e30f;
            for (int c = 0; c < C; c++) mx = fmaxf(mx, W[c]);
            float e[C]; float s = 0.f;
            for (int c = 0; c < C; c++){ e[c] = fexp2((W[c]-mx)*1.44269504089f); s += e[c]; }
            for (int c = 0; c < C; c++) wstar[c] = e[c] / s;
        }
    }
}

// ---------------------------------------------------------------------------
// clause_lds: 256 blocks x 1024 thr, one per CU. Block = (bh, 64-g range).
// Stage the 128KB half-state into LDS, then ALL gathers are ds_read_b32.
// Lane = c (lane>>2, 0..15) x bp (lane&3, word in 16B row). 4 g per wave.
__global__ __launch_bounds__(1024) void clause_lds(
        const __half*  __restrict__ Thh,    // [2][G][8] fp16 shadow
        const ushort*  __restrict__ I16,    // packed indices (C,G,24)
        const float*   __restrict__ wstar,
        const float*   __restrict__ slotPrev,
        float* __restrict__ slotLs,
        float* __restrict__ slotHu,
        float* __restrict__ Hu)             // (G,B) fp32 out
{
    extern __shared__ __align__(16) unsigned sSt[];   // 8192 rows x 16B = 128KB

    const int tix = threadIdx.x;
    const int bh  = blockIdx.x >> 7;              // 0/1: which b-half
    const int g0  = (blockIdx.x & 127) * 64;      // g range start

    // ---- stage half-state into LDS (contiguous uint4 copy)
    const uint4* src = (const uint4*)(Thh + (size_t)bh*G*8);
    uint4* dst = (uint4*)sSt;
    #pragma unroll
    for (int r = 0; r < 8; r++) dst[tix + r*1024] = src[tix + r*1024];

    const float scPrev = 1.0f / fmaxf(waveSlotMax(slotPrev), 1.0f);
    const float sc3 = scPrev * scPrev * scPrev;

    __syncthreads();

    const int lane = tix & 63;
    const int wib  = tix >> 6;        // 0..15
    const int c    = lane >> 2;       // clause 0..15
    const int bp   = lane & 3;        // word (2 halves) within 16B row
    const float wc = wstar[c];
    const int gw0  = g0 + wib*4;      // 4 g per wave

    float lsm = 0.f, humax = 0.f;

    #pragma unroll 2
    for (int gi = 0; gi < 4; gi++){
        const int g = gw0 + gi;
        const uint4* ip = (const uint4*)(I16 + ((size_t)c*G + g)*24);
        uint4 q0 = ip[0], q1 = ip[1], q2 = ip[2];
        unsigned dw[12] = {q0.x,q0.y,q0.z,q0.w, q1.x,q1.y,q1.z,q1.w,
                           q2.x,q2.y,q2.z,q2.w};
        unsigned hv[24];
        #pragma unroll
        for (int i = 0; i < 12; i++){
            hv[2*i]   = sSt[(dw[i] & 0xFFFFu)*4 + bp];
            hv[2*i+1] = sSt[(dw[i] >> 16)*4 + bp];
        }
        float bx[S], by[S];
        #pragma unroll
        for (int s = 0; s < S; s++){
            float2 u0 = __half22float2(*(const __half2*)&hv[3*s+0]);
            float2 u1 = __half22float2(*(const __half2*)&hv[3*s+1]);
            float2 u2 = __half22float2(*(const __half2*)&hv[3*s+2]);
            bx[s] = u0.x*u1.x*u2.x*sc3;
            by[s] = u0.y*u1.y*u2.y*sc3;
        }
        float mx = bx[0], my = by[0];
        #pragma unroll
        for (int s = 1; s < S; s++){ mx = fmaxf(mx, bx[s]); my = fmaxf(my, by[s]); }
        float sx = 0.f, sy = 0.f;
        #pragma unroll
        for (int s = 0; s < S; s++){
            sx += fexp2((bx[s]-mx)*K_E);
            sy += fexp2((by[s]-my)*K_E);
        }
        float lx = mx + GLN2*flog2(sx);
        float ly = my + GLN2*flog2(sy);
        lsm = fmaxf(lsm, fmaxf(lx, ly));

        float hx = wc*lx, hy = wc*ly;
        hx += __shfl_xor(hx, 4); hx += __shfl_xor(hx, 8);
        hx += __shfl_xor(hx, 16); hx += __shfl_xor(hx, 32);
        hy += __shfl_xor(hy, 4); hy += __shfl_xor(hy, 8);
        hy += __shfl_xor(hy, 16); hy += __shfl_xor(hy, 32);
        humax = fmaxf(humax, fmaxf(hx, hy));

        if (c == 0)   // 4 lanes x float2 = the 8 b's of this half
            *(float2*)(Hu + (size_t)g*B + bh*8 + bp*2) = make_float2(hx, hy);
    }

    float wl = waveMax(lsm);
    float wh = waveMax(humax);
    if (lane == 0){
        const int wv = blockIdx.x*16 + wib;
        atomicMaxF(&slotLs[(wv & (NSLOT-1)) << 4], wl);
        atomicMaxF(&slotHu[(wv & (NSLOT-1)) << 4], wh);
    }
}

// ---------------------------------------------------------------------------
// clause_bh: R5-proven flat-gather clause, bh-major shadow (fallback if the
// 128KB dynamic-LDS opt-in is unavailable). One wave per g; j = c-quad, b lane.
__global__ __launch_bounds__(256) void clause_bh(
        const __half*  __restrict__ Thh,    // [2][G][8]
        const ushort*  __restrict__ I16,
        const float*   __restrict__ wstar,
        const float*   __restrict__ slotPrev,
        float* __restrict__ slotLs,
        float* __restrict__ slotHu,
        float* __restrict__ Hu)
{
    const int lane = threadIdx.x & 63;
    const int g    = blockIdx.x*4 + (threadIdx.x >> 6);
    const int j    = lane >> 4;
    const int b    = lane & 15;
    const __half* Tb = Thh + (size_t)(b>>3)*G*8 + (b&7);

    const float scPrev = 1.0f / fmaxf(waveSlotMax(slotPrev), 1.0f);
    const float sc3 = scPrev * scPrev * scPrev;
    const f4 wst4 = *(const f4*)(wstar + j*4);

    float humix = 0.f, lsmax = 0.f;
    #pragma unroll 2
    for (int k = 0; k < 4; k++){
        const int c = j*4 + k;
        const uint4* p = (const uint4*)(I16 + (size_t)(c*G + g)*(S*L));
        uint4 d0 = p[0], d1 = p[1], d2 = p[2];
        unsigned dw[12] = {d0.x,d0.y,d0.z,d0.w, d1.x,d1.y,d1.z,d1.w,
                           d2.x,d2.y,d2.z,d2.w};
        float gv[S*L];
        #pragma unroll
        for (int i = 0; i < 12; i++){
            gv[2*i]   = __half2float(Tb[(size_t)(dw[i] & 0xFFFFu)*8]);
            gv[2*i+1] = __half2float(Tb[(size_t)(dw[i] >> 16)*8]);
        }
        float body[S];
        #pragma unroll
        for (int s = 0; s < S; s++) body[s] = gv[3*s]*gv[3*s+1]*gv[3*s+2]*sc3;

        float m = body[0];
        #pragma unroll
        for (int s = 1; s < S; s++) m = fmaxf(m, body[s]);
        float sum = 0.f;
        #pragma unroll
        for (int s = 0; s < S; s++) sum += fexp2((body[s] - m) * K_E);
        float ls = m + GLN2 * flog2(sum);

        lsmax = fmaxf(lsmax, ls);
        humix = __builtin_fmaf(wst4[k], ls, humix);
    }
    humix += __shfl_xor(humix, 16);
    humix += __shfl_xor(humix, 32);
    if (lane < 16) Hu[(size_t)g*B + lane] = humix;

    float wl = waveMax(lsmax);
    float wh = waveMax(humix);
    if (lane == 0){
        atomicMaxF(&slotLs[(g & (NSLOT-1)) << 4], wl);
        atomicMaxF(&slotHu[(g & (NSLOT-1)) << 4], wh);
    }
}

// Full fallback: fp32 state, unpacked int32 I (tiny-ws path).
__global__ __launch_bounds__(256) void clause_f(
        const float* __restrict__ Tin,
        const int*   __restrict__ I32,
        const float* __restrict__ wstar,
        const float* __restrict__ slotPrev,
        float* __restrict__ slotLs,
        float* __restrict__ slotHu,
        float* __restrict__ Hu)
{
    const int lane = threadIdx.x & 63;
    const int g    = blockIdx.x*4 + (threadIdx.x >> 6);
    const int j    = lane >> 4;
    const int b    = lane & 15;

    const float scPrev = 1.0f / fmaxf(waveSlotMax(slotPrev), 1.0f);
    const float sc3 = scPrev * scPrev * scPrev;
    const f4 wst4 = *(const f4*)(wstar + j*4);

    float humix = 0.f, lsmax = 0.f;
    #pragma unroll 2
    for (int k = 0; k < 4; k++){
        const int c = j*4 + k;
        const int4* p = (const int4*)(I32 + (size_t)(c*G + g)*(S*L));
        int idx[S*L];
        #pragma unroll
        for (int i = 0; i < 6; i++){
            int4 v = p[i];
            idx[4*i] = v.x; idx[4*i+1] = v.y; idx[4*i+2] = v.z; idx[4*i+3] = v.w;
        }
        float gv[S*L];
        #pragma unroll
        for (int t = 0; t < S*L; t++) gv[t] = Tin[idx[t]*B + b];

        float body[S];
        #pragma unroll
        for (int s = 0; s < S; s++) body[s] = gv[3*s]*gv[3*s+1]*gv[3*s+2]*sc3;

        float m = body[0];
        #pragma unroll
        for (int s = 1; s < S; s++) m = fmaxf(m, body[s]);
        float sum = 0.f;
        #pragma unroll
        for (int s = 0; s < S; s++) sum += fexp2((body[s] - m) * K_E);
        float ls = m + GLN2 * flog2(sum);

        lsmax = fmaxf(lsmax, ls);
        humix = __builtin_fmaf(wst4[k], ls, humix);
    }
    humix += __shfl_xor(humix, 16);
    humix += __shfl_xor(humix, 32);
    if (lane < 16) Hu[(size_t)g*B + lane] = humix;

    float wl = waveMax(lsmax);
    float wh = waveMax(humix);
    if (lane == 0){
        atomicMaxF(&slotLs[(g & (NSLOT-1)) << 4], wl);
        atomicMaxF(&slotHu[(g & (NSLOT-1)) << 4], wh);
    }
}

// ---------------------------------------------------------------------------
// Combine: r = (scA*Hu)/max(scA*gmaxHu,1); T = gamma*LSE2(Rn, r); track gmax(T).
template<bool PK>
__global__ __launch_bounds__(256) void combine_kernel(
        const float* __restrict__ Hu,
        const float* __restrict__ Tin,
        const float* __restrict__ slotLs,
        const float* __restrict__ slotHu,
        const float* __restrict__ slotPrev,
        float* __restrict__ Tout,
        __half* __restrict__ Touth,        // bh-major shadow
        float* __restrict__ slotT)
{
    const float scA = 1.0f / fmaxf(waveSlotMax(slotLs), 1.0f);
    const float scB = 1.0f / fmaxf(scA * waveSlotMax(slotHu), 1.0f);
    const float scP = 1.0f / fmaxf(waveSlotMax(slotPrev), 1.0f);

    const int t = blockIdx.x*256 + threadIdx.x;   // over G*B
    float r  = Hu[t] * (scA * scB);
    float Rn = Tin[t] * scP;
    float M  = fmaxf(Rn, r);
    float v  = M + GLN2 * flog2(fexp2((Rn-M)*K_E) + fexp2((r-M)*K_E));
    Tout[t] = v;
    if (PK){
        int g = t >> 4, b = t & 15;
        Touth[((size_t)(b>>3)*G + g)*8 + (b&7)] = __float2half(v);
    }
    float wm = waveMax(v);
    if ((threadIdx.x & 63) == 0)
        atomicMaxF(&slotT[(blockIdx.x & (NSLOT-1)) << 4], wm);
}

// final: out[b*G+g] = T[g*B+b] / max(gmaxT,1)
__global__ void output_kernel(const float* __restrict__ T, const float* __restrict__ slotT,
                              float* __restrict__ out){
    float sc = 1.0f / fmaxf(waveSlotMax(slotT), 1.0f);
    int tid = blockIdx.x*256 + threadIdx.x;   // b*G+g
    int b = tid >> 13;
    int g = tid & (G-1);
    out[tid] = T[g*B + b] * sc;
}

extern "C" void kernel_launch(void* const* d_in, const int* in_sizes, int n_in,
                              void* d_out, int out_size, void* d_ws, size_t ws_size,
                              hipStream_t stream) {
    const float* x = (const float*)d_in[0];
    const float* W = (const float*)d_in[1];
    const int*   I = (const int*)d_in[2];
    // d_in[3] = infer_step (device scalar); fixed at 4 by setup_inputs.

    const size_t baseF  = 16 + 13*ARR;           // wstar + slots
    const size_t packF  = (size_t)C*G*S*L / 2;   // packed I, in float units
    const size_t stateF = (size_t)G*B;
    const size_t halfF  = (size_t)G*B / 2;       // one fp16 shadow, float units
    const bool packed = ws_size >= (baseF + packF + 3*stateF + 2*halfF) * sizeof(float);

    float* ws    = (float*)d_ws;
    float* wstar = ws;
    float* slots = ws + 16;
    ushort* Ipk  = (ushort*)(ws + baseF);
    float* T0    = ws + baseF + (packed ? packF : 0);
    float* T1    = T0 + stateF;
    float* Hu    = T1 + stateF;
    __half* Thh0 = (__half*)(Hu + stateF);       // [2][G][8]
    __half* Thh1 = Thh0 + (size_t)G*B;

    float* out = (float*)d_out;

    // Opt in to 128KB dynamic LDS for clause_lds; fall back if not supported.
    bool ldsOK = false;
    if (packed)
        ldsOK = hipFuncSetAttribute((const void*)clause_lds,
                    hipFuncAttributeMaxDynamicSharedMemorySize, 131072) == hipSuccess;

    if (packed){
        prep_kernel<true><<<(C*G*S*L/4)/256 + (B*G)/256 + 1, 256, 0, stream>>>(
            x, I, W, wstar, slots, Ipk, T0, Thh0);
    } else {
        prep_kernel<false><<<(B*G)/256 + 1, 256, 0, stream>>>(
            x, I, W, wstar, slots, Ipk, T0, Thh0);
    }

    float*  bufs[2]  = {T0, T1};
    __half* bufsh[2] = {Thh0, Thh1};
    for (int s = 0; s < STEPS; s++){
        float*  Tin   = bufs[s & 1];
        float*  Tout  = bufs[(s+1) & 1];
        __half* Tinh  = bufsh[s & 1];
        __half* Touth = bufsh[(s+1) & 1];
        float* slotLs = slots + (s*3 + 0)*ARR;
        float* slotHu = slots + (s*3 + 1)*ARR;
        float* slotT  = slots + (s*3 + 2)*ARR;
        const float* slotPrev = (s == 0) ? (slots + 12*ARR) : (slots + ((s-1)*3 + 2)*ARR);
        if (packed){
            if (ldsOK)
                clause_lds<<<256, 1024, 131072, stream>>>(Tinh, Ipk, wstar, slotPrev,
                                                          slotLs, slotHu, Hu);
            else
                clause_bh<<<G/4, 256, 0, stream>>>(Tinh, Ipk, wstar, slotPrev,
                                                   slotLs, slotHu, Hu);
            combine_kernel<true><<<(G*B)/256, 256, 0, stream>>>(Hu, Tin, slotLs, slotHu,
                                                                slotPrev, Tout, Touth, slotT);
        } else {
            clause_f<<<G/4, 256, 0, stream>>>(Tin, I, wstar, slotPrev,
                                              slotLs, slotHu, Hu);
            combine_kernel<false><<<(G*B)/256, 256, 0, stream>>>(Hu, Tin, slotLs, slotHu,
                                                                 slotPrev, Tout, Touth, slotT);
        }
    }
    output_kernel<<<(B*G)/256, 256, 0, stream>>>(bufs[STEPS & 1],
                                                 slots + ((STEPS-1)*3 + 2)*ARR, out);
}

// Round 11
// 71.930 us; speedup vs baseline: 18.3261x; 1.0847x over previous
//
#include <hip/hip_runtime.h>
#include <hip/hip_fp16.h>

// Problem constants: B=16, G=8192, C=16, S=8, L=3, m=1, infer_step=4
constexpr int B = 16;
constexpr int G = 8192;
constexpr int C = 16;
constexpr int S = 8;
constexpr int L = 3;
constexpr int STEPS = 4;
constexpr int NSLOT = 64;        // max-slots, one per 64B line
constexpr int ARR = NSLOT * 16;  // 1024 floats per slot-array

#define K_E   144.269504088896f   // 1/(gamma*ln2), gamma=0.01
#define GLN2  0.00693147180560f   // gamma*ln2

typedef float f4 __attribute__((ext_vector_type(4)));

__device__ __forceinline__ float fexp2(float x){ return __builtin_amdgcn_exp2f(x); }
__device__ __forceinline__ float flog2(float x){ return __builtin_amdgcn_logf(x); }

__device__ __forceinline__ void atomicMaxF(float* p, float v){
    atomicMax(reinterpret_cast<unsigned int*>(p), __float_as_uint(v));
}

__device__ __forceinline__ float waveMax(float v){
    #pragma unroll
    for (int off = 32; off > 0; off >>= 1)
        v = fmaxf(v, __shfl_down(v, off));
    return v;
}

// Wave-cooperative reduce of 64 spread slots: one gather, shfl_xor tree, broadcast.
__device__ __forceinline__ float waveSlotMax(const float* __restrict__ slots){
    float v = slots[(threadIdx.x & 63) << 4];
    v = fmaxf(v, __shfl_xor(v, 32));
    v = fmaxf(v, __shfl_xor(v, 16));
    v = fmaxf(v, __shfl_xor(v, 8));
    v = fmaxf(v, __shfl_xor(v, 4));
    v = fmaxf(v, __shfl_xor(v, 2));
    v = fmaxf(v, __shfl_xor(v, 1));
    return __builtin_amdgcn_readfirstlane(v);
}

// ---------------------------------------------------------------------------
// prep: pack I -> u16, transpose x -> T0 fp32 + bh-major fp16 shadow, init.
// Shadow layout: Thh[bh][g][8] halves, bh = b>>3, bl = b&7.
template<bool PK>
__global__ __launch_bounds__(256) void prep_kernel(
        const float* __restrict__ x, const int* __restrict__ I,
        const float* __restrict__ W,
        float* __restrict__ wstar, float* __restrict__ slots,
        ushort* __restrict__ Ipk,
        float* __restrict__ T0, __half* __restrict__ Thh0)
{
    constexpr int NPACK = PK ? (C*G*S*L/4)/256 : 0;   // 3072 or 0
    const int bid = blockIdx.x;
    if (PK && bid < NPACK){
        int t = bid*256 + threadIdx.x;
        int4 v = ((const int4*)I)[t];
        ushort4 o;
        o.x = (ushort)v.x; o.y = (ushort)v.y; o.z = (ushort)v.z; o.w = (ushort)v.w;
        ((ushort4*)Ipk)[t] = o;
    } else if (bid < NPACK + (B*G)/256){
        int t = (bid - NPACK)*256 + threadIdx.x;  // t = b*G + g
        int b = t >> 13;
        int g = t & (G-1);
        float v = x[t];
        T0[g*B + b] = v;
        if (PK) Thh0[((size_t)(b>>3)*G + g)*8 + (b&7)] = __float2half(v);
    } else {
        int t = threadIdx.x;
        for (int i = t; i < 13*ARR; i += 256) slots[i] = 0.f;
        if (t == 0){
            slots[12*ARR] = 1.0f;   // identity prev-max array
            float mx = -1e30f;
            for (int c = 0; c < C; c++) mx = fmaxf(mx, W[c]);
            float e[C]; float s = 0.f;
            for (int c = 0; c < C; c++){ e[c] = fexp2((W[c]-mx)*1.44269504089f); s += e[c]; }
            for (int c = 0; c < C; c++) wstar[c] = e[c] / s;
        }
    }
}

// ---------------------------------------------------------------------------
// clause_lds: 256 blocks x 1024 thr (one per CU). Block = (bh, 64-g range).
// Stage the 128KB half-state into LDS; lane = gsub(2b) x c(4b) handles one full
// (c,g) clause: 24 ds_read_b128 whole rows (8 b's at once) — 4x fewer LDS
// instructions than the R10 b32 mapping at identical bytes.
__global__ __launch_bounds__(1024) void clause_lds(
        const __half*  __restrict__ Thh,    // [2][G][8] fp16 shadow
        const ushort*  __restrict__ I16,    // packed indices (C,G,24)
        const float*   __restrict__ wstar,
        const float*   __restrict__ slotPrev,
        float* __restrict__ slotLs,
        float* __restrict__ slotHu,
        float* __restrict__ Hu)             // (G,B) fp32 out
{
    extern __shared__ __align__(16) uint4 sSt4[];   // 8192 rows x 16B = 128KB

    const int tix = threadIdx.x;
    const int bh  = blockIdx.x >> 7;              // 0/1: which b-half
    const int g0  = (blockIdx.x & 127) * 64;      // g range start

    // ---- stage half-state into LDS (contiguous uint4 copy)
    const uint4* src = (const uint4*)(Thh + (size_t)bh*G*8);
    #pragma unroll
    for (int r = 0; r < 8; r++) sSt4[tix + r*1024] = src[tix + r*1024];

    const float scPrev = 1.0f / fmaxf(waveSlotMax(slotPrev), 1.0f);
    const float sc3 = scPrev * scPrev * scPrev;

    __syncthreads();

    const int lane = tix & 63;
    const int wib  = tix >> 6;        // 0..15
    const int c    = lane & 15;       // clause
    const int gsub = lane >> 4;       // 0..3
    const int g    = g0 + wib*4 + gsub;
    const float wc = wstar[c];

    // 24 indices for this (c,g)
    const uint4* ip = (const uint4*)(I16 + ((size_t)c*G + g)*24);
    uint4 q0 = ip[0], q1 = ip[1], q2 = ip[2];
    unsigned dw[12] = {q0.x,q0.y,q0.z,q0.w, q1.x,q1.y,q1.z,q1.w,
                       q2.x,q2.y,q2.z,q2.w};
    int ix[24];
    #pragma unroll
    for (int i = 0; i < 12; i++){
        ix[2*i]   = (int)(dw[i] & 0xFFFFu);
        ix[2*i+1] = (int)(dw[i] >> 16);
    }

    // body[s][bl] for all 8 b's of this half
    float body[S][8];
    #pragma unroll
    for (int s = 0; s < S; s++){
        uint4 r0 = sSt4[ix[3*s+0]];
        uint4 r1 = sSt4[ix[3*s+1]];
        uint4 r2 = sSt4[ix[3*s+2]];
        #pragma unroll
        for (int h = 0; h < 4; h++){
            float2 a  = __half22float2(((const __half2*)&r0)[h]);
            float2 b2 = __half22float2(((const __half2*)&r1)[h]);
            float2 c2 = __half22float2(((const __half2*)&r2)[h]);
            body[s][2*h]   = a.x*b2.x*c2.x*sc3;
            body[s][2*h+1] = a.y*b2.y*c2.y*sc3;
        }
    }

    float hu[8];
    float lsm = 0.f;
    #pragma unroll
    for (int bl = 0; bl < 8; bl++){
        float m = body[0][bl];
        #pragma unroll
        for (int s = 1; s < S; s++) m = fmaxf(m, body[s][bl]);
        float sum = 0.f;
        #pragma unroll
        for (int s = 0; s < S; s++) sum += fexp2((body[s][bl] - m) * K_E);
        float ls = m + GLN2 * flog2(sum);
        lsm = fmaxf(lsm, ls);
        hu[bl] = wc * ls;
    }

    // reduce over c (lane bits 0..3)
    #pragma unroll
    for (int bl = 0; bl < 8; bl++){
        hu[bl] += __shfl_xor(hu[bl], 1);
        hu[bl] += __shfl_xor(hu[bl], 2);
        hu[bl] += __shfl_xor(hu[bl], 4);
        hu[bl] += __shfl_xor(hu[bl], 8);
    }
    float humax = hu[0];
    #pragma unroll
    for (int bl = 1; bl < 8; bl++) humax = fmaxf(humax, hu[bl]);

    if (c == 0){
        f4 v0 = {hu[0], hu[1], hu[2], hu[3]};
        f4 v1 = {hu[4], hu[5], hu[6], hu[7]};
        *(f4*)(Hu + (size_t)g*B + bh*8)     = v0;
        *(f4*)(Hu + (size_t)g*B + bh*8 + 4) = v1;
    }

    float wl = waveMax(lsm);
    float wh = waveMax(humax);
    if (lane == 0){
        const int wv = blockIdx.x*16 + wib;
        atomicMaxF(&slotLs[(wv & (NSLOT-1)) << 4], wl);
        atomicMaxF(&slotHu[(wv & (NSLOT-1)) << 4], wh);
    }
}

// ---------------------------------------------------------------------------
// clause_bh: R5-proven flat-gather clause, bh-major shadow (fallback if the
// 128KB dynamic-LDS opt-in is unavailable). One wave per g; j = c-quad, b lane.
__global__ __launch_bounds__(256) void clause_bh(
        const __half*  __restrict__ Thh,    // [2][G][8]
        const ushort*  __restrict__ I16,
        const float*   __restrict__ wstar,
        const float*   __restrict__ slotPrev,
        float* __restrict__ slotLs,
        float* __restrict__ slotHu,
        float* __restrict__ Hu)
{
    const int lane = threadIdx.x & 63;
    const int g    = blockIdx.x*4 + (threadIdx.x >> 6);
    const int j    = lane >> 4;
    const int b    = lane & 15;
    const __half* Tb = Thh + (size_t)(b>>3)*G*8 + (b&7);

    const float scPrev = 1.0f / fmaxf(waveSlotMax(slotPrev), 1.0f);
    const float sc3 = scPrev * scPrev * scPrev;
    const f4 wst4 = *(const f4*)(wstar + j*4);

    float humix = 0.f, lsmax = 0.f;
    #pragma unroll 2
    for (int k = 0; k < 4; k++){
        const int c = j*4 + k;
        const uint4* p = (const uint4*)(I16 + (size_t)(c*G + g)*(S*L));
        uint4 d0 = p[0], d1 = p[1], d2 = p[2];
        unsigned dw[12] = {d0.x,d0.y,d0.z,d0.w, d1.x,d1.y,d1.z,d1.w,
                           d2.x,d2.y,d2.z,d2.w};
        float gv[S*L];
        #pragma unroll
        for (int i = 0; i < 12; i++){
            gv[2*i]   = __half2float(Tb[(size_t)(dw[i] & 0xFFFFu)*8]);
            gv[2*i+1] = __half2float(Tb[(size_t)(dw[i] >> 16)*8]);
        }
        float body[S];
        #pragma unroll
        for (int s = 0; s < S; s++) body[s] = gv[3*s]*gv[3*s+1]*gv[3*s+2]*sc3;

        float m = body[0];
        #pragma unroll
        for (int s = 1; s < S; s++) m = fmaxf(m, body[s]);
        float sum = 0.f;
        #pragma unroll
        for (int s = 0; s < S; s++) sum += fexp2((body[s] - m) * K_E);
        float ls = m + GLN2 * flog2(sum);

        lsmax = fmaxf(lsmax, ls);
        humix = __builtin_fmaf(wst4[k], ls, humix);
    }
    humix += __shfl_xor(humix, 16);
    humix += __shfl_xor(humix, 32);
    if (lane < 16) Hu[(size_t)g*B + lane] = humix;

    float wl = waveMax(lsmax);
    float wh = waveMax(humix);
    if (lane == 0){
        atomicMaxF(&slotLs[(g & (NSLOT-1)) << 4], wl);
        atomicMaxF(&slotHu[(g & (NSLOT-1)) << 4], wh);
    }
}

// Full fallback: fp32 state, unpacked int32 I (tiny-ws path).
__global__ __launch_bounds__(256) void clause_f(
        const float* __restrict__ Tin,
        const int*   __restrict__ I32,
        const float* __restrict__ wstar,
        const float* __restrict__ slotPrev,
        float* __restrict__ slotLs,
        float* __restrict__ slotHu,
        float* __restrict__ Hu)
{
    const int lane = threadIdx.x & 63;
    const int g    = blockIdx.x*4 + (threadIdx.x >> 6);
    const int j    = lane >> 4;
    const int b    = lane & 15;

    const float scPrev = 1.0f / fmaxf(waveSlotMax(slotPrev), 1.0f);
    const float sc3 = scPrev * scPrev * scPrev;
    const f4 wst4 = *(const f4*)(wstar + j*4);

    float humix = 0.f, lsmax = 0.f;
    #pragma unroll 2
    for (int k = 0; k < 4; k++){
        const int c = j*4 + k;
        const int4* p = (const int4*)(I32 + (size_t)(c*G + g)*(S*L));
        int idx[S*L];
        #pragma unroll
        for (int i = 0; i < 6; i++){
            int4 v = p[i];
            idx[4*i] = v.x; idx[4*i+1] = v.y; idx[4*i+2] = v.z; idx[4*i+3] = v.w;
        }
        float gv[S*L];
        #pragma unroll
        for (int t = 0; t < S*L; t++) gv[t] = Tin[idx[t]*B + b];

        float body[S];
        #pragma unroll
        for (int s = 0; s < S; s++) body[s] = gv[3*s]*gv[3*s+1]*gv[3*s+2]*sc3;

        float m = body[0];
        #pragma unroll
        for (int s = 1; s < S; s++) m = fmaxf(m, body[s]);
        float sum = 0.f;
        #pragma unroll
        for (int s = 0; s < S; s++) sum += fexp2((body[s] - m) * K_E);
        float ls = m + GLN2 * flog2(sum);

        lsmax = fmaxf(lsmax, ls);
        humix = __builtin_fmaf(wst4[k], ls, humix);
    }
    humix += __shfl_xor(humix, 16);
    humix += __shfl_xor(humix, 32);
    if (lane < 16) Hu[(size_t)g*B + lane] = humix;

    float wl = waveMax(lsmax);
    float wh = waveMax(humix);
    if (lane == 0){
        atomicMaxF(&slotLs[(g & (NSLOT-1)) << 4], wl);
        atomicMaxF(&slotHu[(g & (NSLOT-1)) << 4], wh);
    }
}

// ---------------------------------------------------------------------------
// Combine: r = (scA*Hu)/max(scA*gmaxHu,1); T = gamma*LSE2(Rn, r); track gmax(T).
template<bool PK>
__global__ __launch_bounds__(256) void combine_kernel(
        const float* __restrict__ Hu,
        const float* __restrict__ Tin,
        const float* __restrict__ slotLs,
        const float* __restrict__ slotHu,
        const float* __restrict__ slotPrev,
        float* __restrict__ Tout,
        __half* __restrict__ Touth,        // bh-major shadow
        float* __restrict__ slotT)
{
    const float scA = 1.0f / fmaxf(waveSlotMax(slotLs), 1.0f);
    const float scB = 1.0f / fmaxf(scA * waveSlotMax(slotHu), 1.0f);
    const float scP = 1.0f / fmaxf(waveSlotMax(slotPrev), 1.0f);

    const int t = blockIdx.x*256 + threadIdx.x;   // over G*B
    float r  = Hu[t] * (scA * scB);
    float Rn = Tin[t] * scP;
    float M  = fmaxf(Rn, r);
    float v  = M + GLN2 * flog2(fexp2((Rn-M)*K_E) + fexp2((r-M)*K_E));
    Tout[t] = v;
    if (PK){
        int g = t >> 4, b = t & 15;
        Touth[((size_t)(b>>3)*G + g)*8 + (b&7)] = __float2half(v);
    }
    float wm = waveMax(v);
    if ((threadIdx.x & 63) == 0)
        atomicMaxF(&slotT[(blockIdx.x & (NSLOT-1)) << 4], wm);
}

// final: out[b*G+g] = T[g*B+b] / max(gmaxT,1)
__global__ void output_kernel(const float* __restrict__ T, const float* __restrict__ slotT,
                              float* __restrict__ out){
    float sc = 1.0f / fmaxf(waveSlotMax(slotT), 1.0f);
    int tid = blockIdx.x*256 + threadIdx.x;   // b*G+g
    int b = tid >> 13;
    int g = tid & (G-1);
    out[tid] = T[g*B + b] * sc;
}

extern "C" void kernel_launch(void* const* d_in, const int* in_sizes, int n_in,
                              void* d_out, int out_size, void* d_ws, size_t ws_size,
                              hipStream_t stream) {
    const float* x = (const float*)d_in[0];
    const float* W = (const float*)d_in[1];
    const int*   I = (const int*)d_in[2];
    // d_in[3] = infer_step (device scalar); fixed at 4 by setup_inputs.

    const size_t baseF  = 16 + 13*ARR;           // wstar + slots
    const size_t packF  = (size_t)C*G*S*L / 2;   // packed I, in float units
    const size_t stateF = (size_t)G*B;
    const size_t halfF  = (size_t)G*B / 2;       // one fp16 shadow, float units
    const bool packed = ws_size >= (baseF + packF + 3*stateF + 2*halfF) * sizeof(float);

    float* ws    = (float*)d_ws;
    float* wstar = ws;
    float* slots = ws + 16;
    ushort* Ipk  = (ushort*)(ws + baseF);
    float* T0    = ws + baseF + (packed ? packF : 0);
    float* T1    = T0 + stateF;
    float* Hu    = T1 + stateF;
    __half* Thh0 = (__half*)(Hu + stateF);       // [2][G][8]
    __half* Thh1 = Thh0 + (size_t)G*B;

    float* out = (float*)d_out;

    // Opt in to 128KB dynamic LDS for clause_lds; fall back if not supported.
    bool ldsOK = false;
    if (packed)
        ldsOK = hipFuncSetAttribute((const void*)clause_lds,
                    hipFuncAttributeMaxDynamicSharedMemorySize, 131072) == hipSuccess;

    if (packed){
        prep_kernel<true><<<(C*G*S*L/4)/256 + (B*G)/256 + 1, 256, 0, stream>>>(
            x, I, W, wstar, slots, Ipk, T0, Thh0);
    } else {
        prep_kernel<false><<<(B*G)/256 + 1, 256, 0, stream>>>(
            x, I, W, wstar, slots, Ipk, T0, Thh0);
    }

    float*  bufs[2]  = {T0, T1};
    __half* bufsh[2] = {Thh0, Thh1};
    for (int s = 0; s < STEPS; s++){
        float*  Tin   = bufs[s & 1];
        float*  Tout  = bufs[(s+1) & 1];
        __half* Tinh  = bufsh[s & 1];
        __half* Touth = bufsh[(s+1) & 1];
        float* slotLs = slots + (s*3 + 0)*ARR;
        float* slotHu = slots + (s*3 + 1)*ARR;
        float* slotT  = slots + (s*3 + 2)*ARR;
        const float* slotPrev = (s == 0) ? (slots + 12*ARR) : (slots + ((s-1)*3 + 2)*ARR);
        if (packed){
            if (ldsOK)
                clause_lds<<<256, 1024, 131072, stream>>>(Tinh, Ipk, wstar, slotPrev,
                                                          slotLs, slotHu, Hu);
            else
                clause_bh<<<G/4, 256, 0, stream>>>(Tinh, Ipk, wstar, slotPrev,
                                                   slotLs, slotHu, Hu);
            combine_kernel<true><<<(G*B)/256, 256, 0, stream>>>(Hu, Tin, slotLs, slotHu,
                                                                slotPrev, Tout, Touth, slotT);
        } else {
            clause_f<<<G/4, 256, 0, stream>>>(Tin, I, wstar, slotPrev,
                                              slotLs, slotHu, Hu);
            combine_kernel<false><<<(G*B)/256, 256, 0, stream>>>(Hu, Tin, slotLs, slotHu,
                                                                 slotPrev, Tout, Touth, slotT);
        }
    }
    output_kernel<<<(B*G)/256, 256, 0, stream>>>(bufs[STEPS & 1],
                                                 slots + ((STEPS-1)*3 + 2)*ARR, out);
}